// Round 8
// baseline (544.683 us; speedup 1.0000x reference)
//
#include <hip/hip_runtime.h>

// Problem constants
#define B_   2
#define NQ_  8192
#define NK_  8192
#define DIN_ 256
#define DH_  256
#define M_   (B_ * NQ_)   // 16384 flattened rows

typedef _Float16 f16x8 __attribute__((ext_vector_type(8)));
typedef unsigned short u16x8 __attribute__((ext_vector_type(8)));
typedef unsigned short u16x4 __attribute__((ext_vector_type(4)));
typedef unsigned int  u32x4 __attribute__((ext_vector_type(4)));
typedef float f32x16 __attribute__((ext_vector_type(16)));

__device__ __forceinline__ unsigned short f2h(float f) {
    _Float16 h = (_Float16)f;
    return __builtin_bit_cast(unsigned short, h);
}
__device__ __forceinline__ float h2f(unsigned short u) {
    return (float)__builtin_bit_cast(_Float16, u);
}

// ---------------------------------------------------------------------------
// Kernel 1: weight convert + transpose via LDS tile (both sides coalesced).
// wt[mat][n][k] = fp16(W[mat][k][n]).  grid (4,4,3), block 256.
// ---------------------------------------------------------------------------
__global__ void wt_conv(const float* __restrict__ Wq, const float* __restrict__ Wk,
                        const float* __restrict__ Wv, unsigned short* __restrict__ wt) {
    __shared__ float tile[64][65];
    const int mat = blockIdx.z;
    const int k0 = blockIdx.x * 64, n0 = blockIdx.y * 64;
    const float* W = (mat == 0) ? Wq : (mat == 1) ? Wk : Wv;
#pragma unroll
    for (int p = 0; p < 16; ++p) {
        const int idx = p * 256 + threadIdx.x;
        const int r = idx >> 6, c = idx & 63;
        tile[r][c] = W[(k0 + r) * 256 + n0 + c];
    }
    __syncthreads();
#pragma unroll
    for (int p = 0; p < 16; ++p) {
        const int idx = p * 256 + threadIdx.x;
        const int nr = idx >> 6, kc = idx & 63;
        wt[mat * 65536 + (n0 + nr) * 256 + k0 + kc] = f2h(tile[kc][nr]);
    }
}

// ---------------------------------------------------------------------------
// Kernel 2: projections with 1-deep register prefetch on the X row chain.
// ---------------------------------------------------------------------------
__global__ __launch_bounds__(256) void proj(
    const float* __restrict__ xq, const float* __restrict__ xk, const float* __restrict__ xv,
    const float* __restrict__ bq, const float* __restrict__ bk, const float* __restrict__ bv,
    const unsigned short* __restrict__ wt,
    unsigned short* __restrict__ q_emb, unsigned short* __restrict__ k_emb,
    unsigned short* __restrict__ v_emb_t) {
    const int mat = blockIdx.y;
    const float* x    = (mat == 0) ? xq : (mat == 1) ? xk : xv;
    const float* bias = (mat == 0) ? bq : (mat == 1) ? bk : bv;
    const unsigned short* w = wt + mat * 65536;

    const int tid = threadIdx.x;
    const int l = tid & 63, wv = tid >> 6;
    const int pair = wv >> 1, h = wv & 1;
    const int lm = l & 31, lh = l >> 5;
    const int row0 = blockIdx.x * 64;
    const int m = row0 + pair * 32 + lm;

    f32x16 acc[4];
#pragma unroll
    for (int i = 0; i < 4; ++i)
#pragma unroll
        for (int j = 0; j < 16; ++j) acc[i][j] = 0.0f;

    const float4* xrow = (const float4*)(x + (size_t)m * 256 + lh * 8);
    float4 a0 = xrow[0], a1 = xrow[1];
#pragma unroll
    for (int ks = 0; ks < 16; ++ks) {
        float4 n0 = a0, n1 = a1;
        if (ks < 15) { n0 = xrow[(ks + 1) * 4]; n1 = xrow[(ks + 1) * 4 + 1]; }
        u16x8 au;
        au[0] = f2h(a0.x); au[1] = f2h(a0.y); au[2] = f2h(a0.z); au[3] = f2h(a0.w);
        au[4] = f2h(a1.x); au[5] = f2h(a1.y); au[6] = f2h(a1.z); au[7] = f2h(a1.w);
        f16x8 af = __builtin_bit_cast(f16x8, au);
#pragma unroll
        for (int nt = 0; nt < 4; ++nt) {
            f16x8 bfr = *(const f16x8*)(w + (h * 128 + nt * 32 + lm) * 256 + ks * 16 + lh * 8);
            acc[nt] = __builtin_amdgcn_mfma_f32_32x32x16_f16(af, bfr, acc[nt], 0, 0, 0);
        }
        a0 = n0; a1 = n1;
    }

    if (mat < 2) {
        unsigned short* emb = (mat == 0) ? q_emb : k_emb;
#pragma unroll
        for (int nt = 0; nt < 4; ++nt) {
            const int n = h * 128 + nt * 32 + lm;
            const float bsv = bias[n];
#pragma unroll
            for (int r = 0; r < 16; ++r) {
                const int rl = (r & 3) + 8 * (r >> 2) + 4 * lh;
                emb[(size_t)(row0 + pair * 32 + rl) * 256 + n] = f2h(acc[nt][r] + bsv);
            }
        }
    } else {
        const int batch = row0 >> 13;
        const int nqb = (row0 & 8191) + pair * 32;
#pragma unroll
        for (int nt = 0; nt < 4; ++nt) {
            const int n = h * 128 + nt * 32 + lm;
            const float bsv = bias[n];
            unsigned short* dst = v_emb_t + (size_t)batch * DH_ * NQ_ + (size_t)n * NQ_ + nqb;
#pragma unroll
            for (int g = 0; g < 4; ++g) {
                u16x4 pk;
#pragma unroll
                for (int j = 0; j < 4; ++j) pk[j] = f2h(acc[nt][4 * g + j] + bsv);
                *(u16x4*)(dst + 8 * g + 4 * lh) = pk;
            }
        }
    }
}

// ---------------------------------------------------------------------------
// Kernel 3: flash attention, kv-split x2, NO K/V LDS staging.
// MFMA operands fed directly from global (L2/L3-resident):
//   kf: k_emb rows contiguous in d  -> A-frag is a 16B global load.
//   vf: v_emb_t rows contiguous in k -> A-frag is a 16B global load
//       (one 128B line per d-row per iter; h-invariant, loaded once).
// Only P + stats transit LDS (double-buffered) -> ONE barrier per iteration:
//   per-wave order PV(i) -> S(i+1) -> B(i+1) -> PV(i+1) -> S(i+2) guarantees
//   all PV(i) reads of slot c precede S(i+2) writes of slot c.
// grid 512, XCD-swizzled: (batch,split) combo = (bx&7)>>1 so each combo owns
// 2 XCDs -> 2MB K + 2MB V working set fits the 4MB XCD L2.
// block 256 = 4 waves:
//   S phase:  wave (kt = wv>>1, pr = wv&1): 32k x 32q S^T tile, local-max
//             softmax, P + (pm,psum) stats write.
//   PV phase: wave dq = wv (64d quarter) x 64q; per-k-tile rescale
//             exp(pm_kt - mn) folded into pf as f16 scalar.
// ---------------------------------------------------------------------------
#define BN_ 64
#define NSPLIT_ 2
#define KPS_ (NK_ / NSPLIT_)   // 4096 keys per split
#define NT_ (KPS_ / BN_)       // 64 iterations
#define PSTR 144               // 64 q-rows x (128+16) bytes
#define PB_SZ (64 * PSTR)      // 9216
#define LDS_TOTAL (2 * PB_SZ + 2048)   // 20480 B

__global__ __launch_bounds__(256, 2) void flash(
    const unsigned short* __restrict__ q_emb, const unsigned short* __restrict__ k_emb,
    const unsigned short* __restrict__ v_emb_t,
    float* __restrict__ opart, float2* __restrict__ ml) {
    __shared__ __align__(16) char lds[LDS_TOTAL];
    char* pbufs = lds;                          // 2 x [64][144]
    float* stats = (float*)(lds + 2 * PB_SZ);   // 2 x [64][4]: m0,m1,ps0,ps1

    const int tid = threadIdx.x;
    const int l = tid & 63, wv = tid >> 6;  // wv 0..3
    const int lm = l & 31, lh = l >> 5;
    const int kt = wv >> 1, pr = wv & 1;    // S role
    const int dq = wv;                      // PV role: d-quarter

    // XCD-aware swizzle: r = bx&7 ~ XCD (round-robin heuristic).
    const int bx = blockIdx.x;
    const int r = bx & 7, j = bx >> 3;          // j 0..63
    const int combo = r >> 1;                   // 0..3 -> (batch, split)
    const int batch = combo & 1, split = combo >> 1;
    const int t = j + 64 * (r & 1);             // q-tile 0..127
    const int qb = t * 64;
    const int kb0 = split * KPS_;

    const unsigned short* kg = k_emb + (size_t)batch * NQ_ * 256;
    const unsigned short* vg = v_emb_t + (size_t)batch * DH_ * NQ_;

    // Q fragments register-resident for this wave's pr q-half.
    const int mrow = batch * NQ_ + qb + pr * 32 + lm;
    f16x8 qf[16];
#pragma unroll
    for (int ks = 0; ks < 16; ++ks)
        qf[ks] = *(const f16x8*)(q_emb + (size_t)mrow * 256 + ks * 16 + lh * 8);

    // O^T accumulator: [h*2+dt] = q-half h, d-tile dt within quarter dq.
    f32x16 oacc[4];
#pragma unroll
    for (int i = 0; i < 4; ++i)
#pragma unroll
        for (int j2 = 0; j2 < 16; ++j2) oacc[i][j2] = 0.0f;
    float mstat[2] = { -3.0e38f, -3.0e38f };
    float lstat[2] = { 0.0f, 0.0f };

    // global A-operand row bases (lane-invariant parts precomputed)
    const unsigned short* krow_p = kg + (size_t)(kt * 32 + lm) * 256 + lh * 8;
    const unsigned short* vrow0 = vg + (size_t)(dq * 64 + lm) * NQ_ + lh * 8;
    const unsigned short* vrow1 = vg + (size_t)(dq * 64 + 32 + lm) * NQ_ + lh * 8;

    for (int i = 0; i < NT_; ++i) {
        const int kb = kb0 + i * BN_;
        const int cur = i & 1;
        char* pc = pbufs + cur * PB_SZ;
        float* st = stats + cur * 256;

        // ---- S^T tile (kt, pr): A = K rows from GLOBAL, B = qf ----
        f32x16 s;
#pragma unroll
        for (int j2 = 0; j2 < 16; ++j2) s[j2] = 0.0f;
#pragma unroll
        for (int ks = 0; ks < 16; ++ks) {
            f16x8 kf = *(const f16x8*)(krow_p + (size_t)kb * 256 + ks * 16);
            s = __builtin_amdgcn_mfma_f32_32x32x16_f16(kf, qf[ks], s, 0, 0, 0);
        }

        // local tile max (per lane q = pr*32+lm over this tile's 32 k)
        float pm = s[0];
#pragma unroll
        for (int j2 = 1; j2 < 16; ++j2) pm = fmaxf(pm, s[j2]);
        pm = fmaxf(pm, __shfl_xor(pm, 32, 64));

        // exp vs LOCAL max; fp16-round before sum (num/denom consistent)
        float psum = 0.0f;
#pragma unroll
        for (int g = 0; g < 4; ++g) {
            u16x4 pk;
#pragma unroll
            for (int j2 = 0; j2 < 4; ++j2) {
                const unsigned short hh = f2h(__expf(s[g * 4 + j2] - pm));
                pk[j2] = hh;
                psum += h2f(hh);
            }
            *(u16x4*)(pc + (pr * 32 + lm) * PSTR + kt * 64 + g * 16 + lh * 8) = pk;
        }
        psum += __shfl_xor(psum, 32, 64);
        if (lh == 0) {
            st[(pr * 32 + lm) * 4 + kt] = pm;
            st[(pr * 32 + lm) * 4 + 2 + kt] = psum;
        }
        __syncthreads();   // P + stats of tile i visible (sole barrier)

        // ---- vf loads from GLOBAL (h-invariant): d-quarter dq, 128B/row ----
        f16x8 vf[8];
#pragma unroll
        for (int ks2 = 0; ks2 < 4; ++ks2) {
            vf[ks2]     = *(const f16x8*)(vrow0 + kb + ks2 * 16);
            vf[4 + ks2] = *(const f16x8*)(vrow1 + kb + ks2 * 16);
        }

        // ---- PV: this wave's d-quarter dq, both q-halves ----
#pragma unroll
        for (int h = 0; h < 2; ++h) {
            const float4 s4 = *(const float4*)&st[(h * 32 + lm) * 4];
            const float mn = fmaxf(mstat[h], fmaxf(s4.x, s4.y));
            const float alpha = __expf(mstat[h] - mn);
            const float sc0 = __expf(s4.x - mn);
            const float sc1 = __expf(s4.y - mn);
            mstat[h] = mn;
            lstat[h] = lstat[h] * alpha + s4.z * sc0 + s4.w * sc1;
#pragma unroll
            for (int dt = 0; dt < 2; ++dt)
#pragma unroll
                for (int j2 = 0; j2 < 16; ++j2) oacc[h * 2 + dt][j2] *= alpha;

            const _Float16 sch[2] = { (_Float16)sc0, (_Float16)sc1 };
#pragma unroll
            for (int ks2 = 0; ks2 < 4; ++ks2) {
                f16x8 pf = *(const f16x8*)(pc + (h * 32 + lm) * PSTR + ks2 * 32 + lh * 16);
                pf = pf * sch[ks2 >> 1];
#pragma unroll
                for (int dt = 0; dt < 2; ++dt) {
                    oacc[h * 2 + dt] = __builtin_amdgcn_mfma_f32_32x32x16_f16(
                        vf[dt * 4 + ks2], pf, oacc[h * 2 + dt], 0, 0, 0);
                }
            }
        }
    }

    // ---- epilogue: UNNORMALIZED partial O + (m,l) per split ----
#pragma unroll
    for (int h = 0; h < 2; ++h) {
        float* orow = opart + ((size_t)split * M_ + batch * NQ_ + qb + h * 32 + lm) * 256;
#pragma unroll
        for (int dt = 0; dt < 2; ++dt) {
#pragma unroll
            for (int g = 0; g < 4; ++g) {
                float4 o4;
                o4.x = oacc[h * 2 + dt][4 * g + 0];
                o4.y = oacc[h * 2 + dt][4 * g + 1];
                o4.z = oacc[h * 2 + dt][4 * g + 2];
                o4.w = oacc[h * 2 + dt][4 * g + 3];
                *(float4*)(orow + dq * 64 + dt * 32 + 8 * g + 4 * lh) = o4;
            }
        }
    }
    if (wv == 0 && lh == 0) {
#pragma unroll
        for (int h = 0; h < 2; ++h)
            ml[(size_t)split * M_ + batch * NQ_ + qb + h * 32 + lm] =
                make_float2(mstat[h], lstat[h]);
    }
}

// ---------------------------------------------------------------------------
// Kernel 4: combine the 2 kv-splits.  grid 4096, block 256; thread = 1 float4.
// out = (w0*O0 + w1*O1) / (w0*l0 + w1*l1), wX = exp(mX - max(m0,m1)).
// ---------------------------------------------------------------------------
__global__ void combine(const float* __restrict__ opart, const float2* __restrict__ ml,
                        float* __restrict__ out) {
    const int gid = blockIdx.x * 256 + threadIdx.x;   // 0 .. M_*64-1
    const int row = gid >> 6, c = gid & 63;
    const float2 a = ml[row];
    const float2 b = ml[M_ + row];
    const float mx = fmaxf(a.x, b.x);
    const float w0 = __expf(a.x - mx);
    const float w1 = __expf(b.x - mx);
    const float rinv = 1.0f / (w0 * a.y + w1 * b.y);
    const float4 o0 = ((const float4*)opart)[(size_t)row * 64 + c];
    const float4 o1 = ((const float4*)opart)[(size_t)M_ * 64 + (size_t)row * 64 + c];
    float4 o;
    o.x = (w0 * o0.x + w1 * o1.x) * rinv;
    o.y = (w0 * o0.y + w1 * o1.y) * rinv;
    o.z = (w0 * o0.z + w1 * o1.z) * rinv;
    o.w = (w0 * o0.w + w1 * o1.w) * rinv;
    ((float4*)out)[(size_t)row * 64 + c] = o;
}

// ---------------------------------------------------------------------------
extern "C" void kernel_launch(void* const* d_in, const int* in_sizes, int n_in,
                              void* d_out, int out_size, void* d_ws, size_t ws_size,
                              hipStream_t stream) {
    const float* q  = (const float*)d_in[0];
    const float* k  = (const float*)d_in[1];
    const float* v  = (const float*)d_in[2];
    const float* Wq = (const float*)d_in[3];
    const float* bq = (const float*)d_in[4];
    const float* Wk = (const float*)d_in[5];
    const float* bk = (const float*)d_in[6];
    const float* Wv = (const float*)d_in[7];
    const float* bv = (const float*)d_in[8];
    float* out = (float*)d_out;

    unsigned short* wt      = (unsigned short*)d_ws;          // 3*65536 fp16
    unsigned short* q_emb   = wt + 3 * 65536;                 // [16384][256]
    unsigned short* k_emb   = q_emb + (size_t)M_ * DH_;       // [16384][256]
    unsigned short* v_emb_t = k_emb + (size_t)M_ * DH_;       // [2][256][8192]
    float*  opart = (float*)(v_emb_t + (size_t)M_ * DH_);     // [2][16384][256] fp32
    float2* ml    = (float2*)(opart + (size_t)2 * M_ * DH_);  // [2][16384]

    wt_conv<<<dim3(4, 4, 3), 256, 0, stream>>>(Wq, Wk, Wv, wt);
    proj<<<dim3(256, 3), 256, 0, stream>>>(q, k, v, bq, bk, bv, wt, q_emb, k_emb, v_emb_t);
    flash<<<512, 256, 0, stream>>>(q_emb, k_emb, v_emb_t, opart, ml);
    combine<<<4096, 256, 0, stream>>>(opart, ml, out);
}